// Round 16
// baseline (113.287 us; speedup 1.0000x reference)
//
#include <hip/hip_runtime.h>
#include <math.h>

// Problem constants
#define SEQ 4096          // N*N tokens
#define DIM 34
#define NHEAD 2
#define HD 17
#define FFDIM 2048
// (1/sqrt(17)) * log2(e): fold softmax scale + exp2 conversion into Q
#define SC2 0.34990494f

#define EXP2F(x) __builtin_amdgcn_exp2f(x)
#define MFMA16(a, b, c) __builtin_amdgcn_mfma_f32_16x16x32_bf16(a, b, c, 0, 0, 0)

typedef unsigned short u16;
typedef __attribute__((ext_vector_type(8))) short bf16x8;
typedef __attribute__((ext_vector_type(4))) float f32x4;

__device__ inline u16 f2bf(float f) {
    uint32_t u = __builtin_bit_cast(uint32_t, f);
    u += 0x7fffu + ((u >> 16) & 1u);
    return (u16)(u >> 16);
}
__device__ inline uint32_t pack2(float a, float b) {
    uint32_t ua = __builtin_bit_cast(uint32_t, a);
    ua += 0x7fffu + ((ua >> 16) & 1u);
    uint32_t ub = __builtin_bit_cast(uint32_t, b);
    ub += 0x7fffu + ((ub >> 16) & 1u);
    return (ua >> 16) | (ub & 0xffff0000u);
}

#define W1B_ELEMS (FFDIM * 64)       // 131072
#define W2B_ELEMS (48 * FFDIM)       // 98304
#define NWCONV 448                   // repack blocks (ride in attn l0 grid)
#define NQT (SEQ / 16)               // 256 attention q-tiles

// ---------------------------------------------------------------------------
// Kernel 1: wm_pre — conv+seq+qkv(l0), 256 blocks x 16 tokens.
// Fixed-offset softmax: Q pad col 17 = -8, K pad col 17 = 1 -> QK MFMA emits
// (score_log2 - 8) directly. Scores bounded => exact (offset-invariant).
// ---------------------------------------------------------------------------
__global__ __launch_bounds__(1024) void wm_pre(
    const float* __restrict__ obs,
    const float* __restrict__ c1w, const float* __restrict__ c1b,
    const float* __restrict__ c2w, const float* __restrict__ c2b,
    const float* __restrict__ in_w, const float* __restrict__ in_b,   // layer 0
    float* __restrict__ x, u16* __restrict__ Qb, u16* __restrict__ Kb,
    u16* __restrict__ Vc, u16* __restrict__ V16)
{
    const int tid = threadIdx.x;
    __shared__ float obsp[2][10][10];
    __shared__ float h1p[16][10][10];
    __shared__ float cs[64][17];
    const int t0 = blockIdx.x * 16;          // 256 blocks x 16 tokens

    for (int e = tid; e < 200; e += 1024) ((float*)obsp)[e] = 0.f;
    for (int e = tid; e < 1600; e += 1024) ((float*)h1p)[e] = 0.f;
    __syncthreads();
    if (tid < 128) {
        int i = tid >> 6, n = tid & 63, y = n >> 3, xx = n & 7;
        obsp[i][y + 1][xx + 1] = obs[tid];
    }
    __syncthreads();
    {   // conv1
        int o = tid >> 6, n = tid & 63, y = n >> 3, xx = n & 7;
        float a = c1b[o];
        #pragma unroll
        for (int i = 0; i < 2; ++i)
            #pragma unroll
            for (int ky = 0; ky < 3; ++ky)
                #pragma unroll
                for (int kx = 0; kx < 3; ++kx)
                    a = fmaf(obsp[i][y + ky][xx + kx], c1w[((o*2 + i)*3 + ky)*3 + kx], a);
        h1p[o][y + 1][xx + 1] = fmaxf(a, 0.f);
    }
    __syncthreads();
    {   // conv2 -> cs[n][o]
        int o = tid >> 6, n = tid & 63, y = n >> 3, xx = n & 7;
        float a = c2b[o];
        #pragma unroll
        for (int i = 0; i < 16; ++i)
            #pragma unroll
            for (int ky = 0; ky < 3; ++ky)
                #pragma unroll
                for (int kx = 0; kx < 3; ++kx)
                    a = fmaf(h1p[i][y + ky][xx + kx], c2w[((o*16 + i)*3 + ky)*3 + kx], a);
        cs[n][o] = fmaxf(a, 0.f);
    }
    __syncthreads();
    for (int e = tid; e < 16 * DIM; e += 1024) {
        int tl = e / DIM, d = e % DIM;
        int t = t0 + tl, i = t >> 6, j = t & 63;
        float v;
        if (d < 16)       v = cs[i][d];
        else if (d < 32)  v = cs[j][d - 16];
        else if (d == 32) v = (float)((i >> 3) - (j >> 3)) * (1.0f / 3.5f);
        else              v = (float)((i & 7) - (j & 7)) * (1.0f / 3.5f);
        x[(size_t)t0 * DIM + e] = v;
    }
    // emit layer-0 qkv for 16 tokens. Pad col 17: Q=-8, K=1.
    for (int ii = 0; ii < 3; ++ii) {
        int e = tid + ii * 1024;
        if (e >= 16 * 162) break;
        int t = t0 + (e & 15), slot = e >> 4;
        int i = t >> 6, j = t & 63;
        float dx = (float)((i >> 3) - (j >> 3)) * (1.0f / 3.5f);
        float dy = (float)((i & 7) - (j & 7)) * (1.0f / 3.5f);
        if (slot < 128) {
            int isK = slot >> 6, h2 = (slot >> 5) & 1, hs = slot & 31;
            float val = 0.f;
            if (hs < HD) {
                int row = isK*DIM + h2*HD + hs;
                const float* wr = in_w + row*DIM;
                float a = in_b[row];
                #pragma unroll
                for (int d = 0; d < 16; ++d) a = fmaf(cs[i][d], wr[d], a);
                #pragma unroll
                for (int d = 0; d < 16; ++d) a = fmaf(cs[j][d], wr[16 + d], a);
                a = fmaf(dx, wr[32], a);
                a = fmaf(dy, wr[33], a);
                val = isK ? a : a * SC2;
            } else if (hs == HD) {
                val = isK ? 1.0f : -8.0f;     // fixed softmax offset
            }
            u16* dst = isK ? Kb : Qb;
            dst[(((size_t)h2*SEQ + t) << 5) + hs] = f2bf(val);
        } else {
            int s = slot - 128;
            int h2 = s >= HD, dd = s - h2*HD;
            int row = 2*DIM + h2*HD + dd;
            const float* wr = in_w + row*DIM;
            float a = in_b[row];
            #pragma unroll
            for (int d = 0; d < 16; ++d) a = fmaf(cs[i][d], wr[d], a);
            #pragma unroll
            for (int d = 0; d < 16; ++d) a = fmaf(cs[j][d], wr[16 + d], a);
            a = fmaf(dx, wr[32], a);
            a = fmaf(dy, wr[33], a);
            u16 v = f2bf(a);
            if (dd == 16) V16[h2*SEQ + t] = v;
            else {
                int c = t >> 5, g = (t >> 3) & 3, ix = t & 7;
                Vc[((((size_t)h2*128 + c)*4 + g)*16 + dd)*8 + ix] = v;
            }
        }
    }
}

// ---------------------------------------------------------------------------
// Kernel 2: wm_attn3 — MFMA flash attention (fixed-offset softmax, lsum via
// ones-row PV) + out-proj + residual + LN1, in-place on x. 16 waves: wave wv
// -> head wv>>3, key range (wv&7)*512. Layer-0 launch carries NWCONV extra
// blocks (qt >= NQT) that repack FFN weights to bf16 and exit.
// ---------------------------------------------------------------------------
__global__ __launch_bounds__(1024) void wm_attn3(const u16* __restrict__ Qb,
        const u16* __restrict__ Kb, const u16* __restrict__ Vc,
        const u16* __restrict__ V16, float* __restrict__ x,
        const float* __restrict__ ow, const float* __restrict__ obias,
        const float* __restrict__ g, const float* __restrict__ be,
        const float* __restrict__ w1a, const float* __restrict__ b1a, const float* __restrict__ w2a,
        const float* __restrict__ w1b, const float* __restrict__ b1b, const float* __restrict__ w2b,
        u16* __restrict__ W1A, u16* __restrict__ W2A,
        u16* __restrict__ W1B, u16* __restrict__ W2B)
{
    const int qt = blockIdx.x;
    const int tid = threadIdx.x;
    if (qt >= NQT) {
        // ---- weight repack (layer-0 launch only) ----
        int id = (qt - NQT) * 1024 + tid;
        const int half = W1B_ELEMS + W2B_ELEMS;
        const float* w1 = w1a; const float* b1 = b1a; const float* w2 = w2a;
        u16* W1 = W1A; u16* W2 = W2A;
        if (id >= half) { id -= half; w1 = w1b; b1 = b1b; w2 = w2b; W1 = W1B; W2 = W2B; }
        if (id < W1B_ELEMS) {
            int n = id >> 6, c = id & 63;
            float v = (c < DIM) ? w1[n*DIM + c] : ((c == DIM) ? b1[n] : 0.f);
            W1[id] = f2bf(v);
        } else {
            int e = id - W1B_ELEMS;
            int n = e >> 11;
            float v = (n < DIM) ? w2[(n << 11) + (e & 2047)] : 0.f;
            W2[e] = f2bf(v);
        }
        return;
    }
    const int wv = tid >> 6, l = tid & 63;
    const int h = wv >> 3, rr = wv & 7;
    const int q = l & 15, gg = l >> 4;

    __shared__ float red[16][64][7];   // {lsum, olo0..3, ohi0}
    __shared__ float os[16][DIM];
    __shared__ float ys[16][DIM];
    __shared__ float stats[16][2];

    const u16* Qh = Qb + (((size_t)h*SEQ + qt*16 + q) << 5) + 8*gg;
    const u16* Kh = Kb + ((size_t)h*SEQ << 5);
    const u16* Vh = Vc + (size_t)h*128*512;
    const u16* V6 = V16 + (size_t)h*SEQ;

    const bf16x8 qf = *(const bf16x8*)Qh;
    const f32x4 zero4 = {0.f, 0.f, 0.f, 0.f};
    bf16x8 onesv;
    { union { uint32_t u[4]; bf16x8 v; } o1;
      o1.u[0] = o1.u[1] = o1.u[2] = o1.u[3] = 0x3F803F80u; onesv = o1.v; }

    f32x4 olo = zero4, ohi = zero4;
    const int srcA = q + 32*(gg & 1);
    const int srcB = srcA + 16;
    const bool hi = (gg >= 2);

    for (int it = 0; it < 8; ++it) {
        const int cA = rr*16 + it*2;
        const int k0 = cA * 32;
        bf16x8 kf0 = *(const bf16x8*)(Kh + ((size_t)(k0 + q) << 5) + 8*gg);
        bf16x8 kf1 = *(const bf16x8*)(Kh + ((size_t)(k0 + 16 + q) << 5) + 8*gg);
        bf16x8 kf2 = *(const bf16x8*)(Kh + ((size_t)(k0 + 32 + q) << 5) + 8*gg);
        bf16x8 kf3 = *(const bf16x8*)(Kh + ((size_t)(k0 + 48 + q) << 5) + 8*gg);
        f32x4 s0 = MFMA16(kf0, qf, zero4);
        f32x4 s1 = MFMA16(kf1, qf, zero4);
        f32x4 s2 = MFMA16(kf2, qf, zero4);
        f32x4 s3 = MFMA16(kf3, qf, zero4);
        float pa0 = EXP2F(s0[0]), pa1 = EXP2F(s0[1]), pa2 = EXP2F(s0[2]), pa3 = EXP2F(s0[3]);
        float pa4 = EXP2F(s1[0]), pa5 = EXP2F(s1[1]), pa6 = EXP2F(s1[2]), pa7 = EXP2F(s1[3]);
        float pb0 = EXP2F(s2[0]), pb1 = EXP2F(s2[1]), pb2 = EXP2F(s2[2]), pb3 = EXP2F(s2[3]);
        float pb4 = EXP2F(s3[0]), pb5 = EXP2F(s3[1]), pb6 = EXP2F(s3[2]), pb7 = EXP2F(s3[3]);
        {   // chunk A
            uint32_t a0t0 = pack2(pa0, pa1), a1t0 = pack2(pa2, pa3);
            uint32_t a0t1 = pack2(pa4, pa5), a1t1 = pack2(pa6, pa7);
            uint32_t w0a = (uint32_t)__shfl((int)a0t0, srcA), w0b = (uint32_t)__shfl((int)a0t1, srcA);
            uint32_t w1a_ = (uint32_t)__shfl((int)a1t0, srcA), w1b_ = (uint32_t)__shfl((int)a1t1, srcA);
            uint32_t w2a_ = (uint32_t)__shfl((int)a0t0, srcB), w2b_ = (uint32_t)__shfl((int)a0t1, srcB);
            uint32_t w3a = (uint32_t)__shfl((int)a1t0, srcB), w3b = (uint32_t)__shfl((int)a1t1, srcB);
            union { uint32_t u[4]; bf16x8 v; } pu;
            pu.u[0] = hi ? w0b : w0a;
            pu.u[1] = hi ? w1b_ : w1a_;
            pu.u[2] = hi ? w2b_ : w2a_;
            pu.u[3] = hi ? w3b : w3a;
            bf16x8 vf = *(const bf16x8*)(Vh + (size_t)(cA*4 + gg)*128 + q*8);
            bf16x8 v6 = {};
            if (q == 0) v6 = *(const bf16x8*)(V6 + k0 + 8*gg);
            else if (q == 1) v6 = onesv;          // row 1 = ones -> ohi[1] = lsum
            olo = MFMA16(vf, pu.v, olo);
            ohi = MFMA16(v6, pu.v, ohi);
        }
        {   // chunk B
            uint32_t a0t0 = pack2(pb0, pb1), a1t0 = pack2(pb2, pb3);
            uint32_t a0t1 = pack2(pb4, pb5), a1t1 = pack2(pb6, pb7);
            uint32_t w0a = (uint32_t)__shfl((int)a0t0, srcA), w0b = (uint32_t)__shfl((int)a0t1, srcA);
            uint32_t w1a_ = (uint32_t)__shfl((int)a1t0, srcA), w1b_ = (uint32_t)__shfl((int)a1t1, srcA);
            uint32_t w2a_ = (uint32_t)__shfl((int)a0t0, srcB), w2b_ = (uint32_t)__shfl((int)a0t1, srcB);
            uint32_t w3a = (uint32_t)__shfl((int)a1t0, srcB), w3b = (uint32_t)__shfl((int)a1t1, srcB);
            union { uint32_t u[4]; bf16x8 v; } pu;
            pu.u[0] = hi ? w0b : w0a;
            pu.u[1] = hi ? w1b_ : w1a_;
            pu.u[2] = hi ? w2b_ : w2a_;
            pu.u[3] = hi ? w3b : w3a;
            bf16x8 vf = *(const bf16x8*)(Vh + (size_t)((cA + 1)*4 + gg)*128 + q*8);
            bf16x8 v6 = {};
            if (q == 0) v6 = *(const bf16x8*)(V6 + k0 + 32 + 8*gg);
            else if (q == 1) v6 = onesv;
            olo = MFMA16(vf, pu.v, olo);
            ohi = MFMA16(v6, pu.v, ohi);
        }
    }

    {
        float* r = red[wv][l];
        r[0] = ohi[1];                  // lsum partial (nonzero on gg==0 lanes)
        r[1] = olo[0]; r[2] = olo[1]; r[3] = olo[2]; r[4] = olo[3];
        r[5] = ohi[0];
    }
    __syncthreads();
    if (rr == 0) {
        float lt = 0.f, o0 = 0.f, o1 = 0.f, o2 = 0.f, o3 = 0.f, o6 = 0.f;
        #pragma unroll
        for (int p = 0; p < 8; ++p) {
            float* r = red[wv + p][l];
            lt += r[0]; o0 += r[1]; o1 += r[2]; o2 += r[3]; o3 += r[4]; o6 += r[5];
        }
        lt += __shfl_xor(lt, 16);
        lt += __shfl_xor(lt, 32);
        float inv = 1.f / lt;
        os[q][h*HD + 4*gg + 0] = o0*inv;
        os[q][h*HD + 4*gg + 1] = o1*inv;
        os[q][h*HD + 4*gg + 2] = o2*inv;
        os[q][h*HD + 4*gg + 3] = o3*inv;
        if (gg == 0) os[q][h*HD + 16] = o6*inv;
    }
    __syncthreads();
    // out-proj + residual
    for (int e = tid; e < 16 * DIM; e += 1024) {
        int tt = e / DIM, d = e % DIM;
        const float* wr = ow + d*DIM;
        float acc = obias[d];
        #pragma unroll
        for (int k = 0; k < DIM; ++k) acc = fmaf(os[tt][k], wr[k], acc);
        ys[tt][d] = x[(size_t)(qt*16 + tt)*DIM + d] + acc;
    }
    __syncthreads();
    if (tid < 16) {
        float s1 = 0.f, s2 = 0.f;
        #pragma unroll
        for (int d = 0; d < DIM; ++d) { float v = ys[tid][d]; s1 += v; s2 += v*v; }
        float mean = s1 * (1.0f / DIM);
        float var  = s2 * (1.0f / DIM) - mean*mean;
        stats[tid][0] = mean;
        stats[tid][1] = rsqrtf(var + 1e-5f);
    }
    __syncthreads();
    for (int e = tid; e < 16 * DIM; e += 1024) {
        int tt = e / DIM, d = e % DIM;
        x[(size_t)(qt*16 + tt)*DIM + d] = (ys[tt][d] - stats[tt][0]) * stats[tt][1] * g[d] + be[d];
    }
}

// ---------------------------------------------------------------------------
// Kernel 3: wm_ff3 — MFMA fused FFN + residual + LN2 (+ optional next-layer
// QKV emit). 8 tokens/block, 512 blocks, ~60KB LDS -> 2 blocks/CU.
// ---------------------------------------------------------------------------
__global__ __launch_bounds__(1024, 8) void wm_ff3(float* __restrict__ x,
        const u16* __restrict__ W1b, const u16* __restrict__ W2b,
        const float* __restrict__ b2, const float* __restrict__ g,
        const float* __restrict__ be,
        const float* __restrict__ in_w, const float* __restrict__ in_b,
        u16* __restrict__ Qb, u16* __restrict__ Kb,
        u16* __restrict__ Vc, u16* __restrict__ V16, int do_qkv)
{
    __shared__ u16 Hs[16][8][128];       // 32 KB, wave-private, XOR-swizzled
    __shared__ float red[16][8][52];     // 26.6 KB
    __shared__ float ys[8][DIM];
    __shared__ float stats[8][2];
    const int tid = threadIdx.x, wv = tid >> 6, l = tid & 63;
    const int q = l & 15, g4 = l >> 4;
    const int t0 = blockIdx.x * 8;

    // A-fragments: token row = t0+q (rows 8..15 zero)
    union { uint32_t u[4]; bf16x8 v; } a0, a1;
    a0.u[0] = 0; a0.u[1] = 0; a0.u[2] = 0; a0.u[3] = 0;
    a1.u[0] = 0; a1.u[1] = 0; a1.u[2] = 0; a1.u[3] = 0;
    if (q < 8) {
        const float* xr = x + (size_t)(t0 + q) * DIM;
        #pragma unroll
        for (int j = 0; j < 4; ++j)
            a0.u[j] = pack2(xr[g4*8 + 2*j], xr[g4*8 + 2*j + 1]);
        if (g4 == 0) {
            a1.u[0] = pack2(xr[32], xr[33]);
            a1.u[1] = pack2(1.0f, 0.f);      // col 34 = bias slot
        }
    }
    const f32x4 zero4 = {0.f, 0.f, 0.f, 0.f};

    const int hbase = wv * 128;
    #pragma unroll
    for (int nt = 0; nt < 8; ++nt) {
        const u16* brow = W1b + (size_t)(hbase + nt*16 + q) * 64 + g4*8;
        bf16x8 b0 = *(const bf16x8*)brow;
        bf16x8 b1f = *(const bf16x8*)(brow + 32);
        f32x4 c = MFMA16(a0.v, b0, zero4);
        c = MFMA16(a1.v, b1f, c);
        if (g4 < 2) {   // token rows 0..7 only
            #pragma unroll
            for (int r = 0; r < 4; ++r) {
                int mm = 4*g4 + r;
                int byte = ((nt*16 + q) * 2) ^ (mm << 5);
                *(u16*)((char*)&Hs[wv][mm][0] + byte) = f2bf(fmaxf(c[r], 0.f));
            }
        }
    }
    asm volatile("s_waitcnt lgkmcnt(0)" ::: "memory");
    __builtin_amdgcn_sched_barrier(0);
    f32x4 acc0 = zero4, acc1 = zero4, acc2 = zero4;
    #pragma unroll
    for (int ks = 0; ks < 4; ++ks) {
        bf16x8 af = {};
        if (q < 8) {
            int byte = (ks*64 + g4*16) ^ (q << 5);
            af = *(const bf16x8*)((char*)&Hs[wv][q][0] + byte);
        }
        const u16* bp = W2b + (size_t)q * FFDIM + hbase + ks*32 + g4*8;
        acc0 = MFMA16(af, *(const bf16x8*)bp, acc0);
        acc1 = MFMA16(af, *(const bf16x8*)(bp + 16*FFDIM), acc1);
        acc2 = MFMA16(af, *(const bf16x8*)(bp + 32*FFDIM), acc2);
    }
    if (g4 < 2) {
        #pragma unroll
        for (int r = 0; r < 4; ++r) {
            red[wv][4*g4 + r][q]      = acc0[r];
            red[wv][4*g4 + r][16 + q] = acc1[r];
            red[wv][4*g4 + r][32 + q] = acc2[r];
        }
    }
    __syncthreads();
    for (int e = tid; e < 8*DIM; e += 1024) {
        int tt = e / DIM, d = e % DIM;
        float v = x[(size_t)(t0 + tt)*DIM + d] + b2[d];
        #pragma unroll
        for (int w = 0; w < 16; ++w) v += red[w][tt][d];
        ys[tt][d] = v;
    }
    __syncthreads();
    if (tid < 8) {
        float s1 = 0.f, s2 = 0.f;
        #pragma unroll
        for (int d = 0; d < DIM; ++d) { float v = ys[tid][d]; s1 += v; s2 += v * v; }
        float mean = s1 * (1.0f / DIM);
        float var  = s2 * (1.0f / DIM) - mean * mean;
        stats[tid][0] = mean;
        stats[tid][1] = rsqrtf(var + 1e-5f);
    }
    __syncthreads();
    for (int e = tid; e < 8*DIM; e += 1024) {
        int tt = e / DIM, d = e % DIM;
        float v = (ys[tt][d] - stats[tt][0]) * stats[tt][1] * g[d] + be[d];
        x[(size_t)(t0 + tt)*DIM + d] = v;
        ys[tt][d] = v;                   // final x tile kept in LDS for qkv
    }
    if (do_qkv) {
        __syncthreads();
        {
            int e = tid;
            if (e < 8*102) {
                int r = e >> 3, tt = e & 7;
                const float* wr = in_w + r*DIM;
                float a = in_b[r];
                #pragma unroll
                for (int d = 0; d < DIM; ++d) a = fmaf(ys[tt][d], wr[d], a);
                int tg = t0 + tt;
                if (r < 68) {
                    int rq = (r < 34) ? r : r - 34;
                    int h2 = rq >= HD, hs = rq - h2*HD;
                    u16 v = f2bf((r < 34) ? a*SC2 : a);
                    u16* dst = (r < 34) ? Qb : Kb;
                    dst[(((size_t)h2*SEQ + tg) << 5) + hs] = v;
                } else {
                    int rv = r - 68;
                    int h2 = rv >= HD, dd = rv - h2*HD;
                    u16 v = f2bf(a);
                    if (dd == 16) V16[h2*SEQ + tg] = v;
                    else {
                        int c = tg >> 5, gg = (tg >> 3) & 3, ix = tg & 7;
                        Vc[((((size_t)h2*128 + c)*4 + gg)*16 + dd)*8 + ix] = v;
                    }
                }
            }
        }
    }
}

// ---------------------------------------------------------------------------
// Kernel 4: final head (+ agent argmax + action embedding)
// ---------------------------------------------------------------------------
__global__ __launch_bounds__(64) void wm_final(const float* __restrict__ x,
        const float* __restrict__ obs, const int* __restrict__ action,
        const float* __restrict__ aw, const float* __restrict__ ab,
        const float* __restrict__ hw, const float* __restrict__ hb,
        float* __restrict__ out)
{
    __shared__ float hv[DIM];
    __shared__ float saemb[8];
    __shared__ int sai;
    const int tid = threadIdx.x;
    {
        float v = obs[tid];
        float mx = v;
        for (int off = 32; off; off >>= 1) mx = fmaxf(mx, __shfl_xor(mx, off));
        unsigned long long mask = __ballot(v == mx);
        if (tid == 0) sai = (int)(__ffsll(mask) - 1);
    }
    if (tid < 8) {
        int act = *action;
        saemb[tid] = fmaxf(aw[tid*4 + act] + ab[tid], 0.f);
    }
    __syncthreads();
    const int ai = sai;
    if (tid < DIM) {
        float s = 0.f;
        for (int r = 0; r < 64; ++r) s += x[(size_t)(ai*64 + r)*DIM + tid];
        hv[tid] = s * (1.0f / 64.0f);
    }
    __syncthreads();
    if (tid < 16) {
        float a = hb[tid];
        #pragma unroll
        for (int d = 0; d < DIM; ++d) a = fmaf(hv[d], hw[tid*42 + d], a);
        #pragma unroll
        for (int j = 0; j < 8; ++j) a = fmaf(saemb[j], hw[tid*42 + DIM + j], a);
        out[tid] = a;
    }
}

// ---------------------------------------------------------------------------
extern "C" void kernel_launch(void* const* d_in, const int* in_sizes, int n_in,
                              void* d_out, int out_size, void* d_ws, size_t ws_size,
                              hipStream_t stream)
{
    const float* obs    = (const float*)d_in[0];
    const int*   action = (const int*)  d_in[1];

    float* ws   = (float*)d_ws;
    float* x    = ws + 1056;                // 4096*34
    float* o    = x + SEQ * DIM;            // (unused spacing)
    u16*   Qb   = (u16*)(o + SEQ * DIM);    // 2*4096*32 bf16
    u16*   Kb   = Qb + 2 * SEQ * 32;
    u16*   Vc   = Kb + 2 * SEQ * 32;        // 2*128*4*16*8 bf16
    u16*   V16  = Vc + 2 * 128 * 512;       // 2*4096 bf16
    u16*   W1b0 = V16 + 2 * SEQ;
    u16*   W2b0 = W1b0 + W1B_ELEMS;
    u16*   W1b1 = W2b0 + W2B_ELEMS;
    u16*   W2b1 = W1b1 + W1B_ELEMS;

    wm_pre<<<256, 1024, 0, stream>>>(
        obs, (const float*)d_in[2], (const float*)d_in[3],
        (const float*)d_in[4], (const float*)d_in[5],
        (const float*)d_in[6], (const float*)d_in[7],
        x, Qb, Kb, Vc, V16);

    // layer 0 attn (+ hidden weight repack in extra blocks)
    wm_attn3<<<NQT + NWCONV, 1024, 0, stream>>>(Qb, Kb, Vc, V16, x,
        (const float*)d_in[8], (const float*)d_in[9],
        (const float*)d_in[14], (const float*)d_in[15],
        (const float*)d_in[10], (const float*)d_in[11], (const float*)d_in[12],
        (const float*)d_in[22], (const float*)d_in[23], (const float*)d_in[24],
        W1b0, W2b0, W1b1, W2b1);

    wm_ff3<<<SEQ / 8, 1024, 0, stream>>>(x, W1b0, W2b0,
        (const float*)d_in[13], (const float*)d_in[16], (const float*)d_in[17],
        (const float*)d_in[18], (const float*)d_in[19],
        Qb, Kb, Vc, V16, 1);

    // layer 1 attn (no repack blocks)
    wm_attn3<<<NQT, 1024, 0, stream>>>(Qb, Kb, Vc, V16, x,
        (const float*)d_in[20], (const float*)d_in[21],
        (const float*)d_in[26], (const float*)d_in[27],
        (const float*)d_in[10], (const float*)d_in[11], (const float*)d_in[12],
        (const float*)d_in[22], (const float*)d_in[23], (const float*)d_in[24],
        W1b0, W2b0, W1b1, W2b1);

    wm_ff3<<<SEQ / 8, 1024, 0, stream>>>(x, W1b1, W2b1,
        (const float*)d_in[25], (const float*)d_in[28], (const float*)d_in[29],
        (const float*)d_in[18], (const float*)d_in[19],
        Qb, Kb, Vc, V16, 0);

    wm_final<<<1, 64, 0, stream>>>(x, obs, action,
        (const float*)d_in[30], (const float*)d_in[31],
        (const float*)d_in[32], (const float*)d_in[33], (float*)d_out);
}

// Round 17
// 95.836 us; speedup vs baseline: 1.1821x; 1.1821x over previous
//
#include <hip/hip_runtime.h>
#include <math.h>

// Problem constants
#define SEQ 4096          // N*N tokens
#define DIM 34
#define NHEAD 2
#define HD 17
#define FFDIM 2048
// (1/sqrt(17)) * log2(e): fold softmax scale + exp2 conversion into Q
#define SC2 0.34990494f

#define EXP2F(x) __builtin_amdgcn_exp2f(x)
#define MFMA16(a, b, c) __builtin_amdgcn_mfma_f32_16x16x32_bf16(a, b, c, 0, 0, 0)

typedef unsigned short u16;
typedef __attribute__((ext_vector_type(8))) short bf16x8;
typedef __attribute__((ext_vector_type(4))) float f32x4;

__device__ inline u16 f2bf(float f) {
    uint32_t u = __builtin_bit_cast(uint32_t, f);
    u += 0x7fffu + ((u >> 16) & 1u);
    return (u16)(u >> 16);
}
__device__ inline uint32_t pack2(float a, float b) {
    uint32_t ua = __builtin_bit_cast(uint32_t, a);
    ua += 0x7fffu + ((ua >> 16) & 1u);
    uint32_t ub = __builtin_bit_cast(uint32_t, b);
    ub += 0x7fffu + ((ub >> 16) & 1u);
    return (ua >> 16) | (ub & 0xffff0000u);
}

#define W1B_ELEMS (FFDIM * 64)       // 131072
#define W2B_ELEMS (48 * FFDIM)       // 98304
#define NWCONV 448                   // repack blocks (ride in attn3 l0 grid)
#define NQT (SEQ / 16)               // 256 attention q-tiles

// ---------------------------------------------------------------------------
// Kernel 1: wm_pre — conv+seq+qkv(l0), 64 blocks.
// Fixed-offset softmax: Q pad col 17 = -8, K pad col 17 = 1 -> QK MFMA emits
// (score_log2 - 8) directly. Scores bounded => exact (offset-invariant).
// ---------------------------------------------------------------------------
__global__ __launch_bounds__(1024) void wm_pre(
    const float* __restrict__ obs,
    const float* __restrict__ c1w, const float* __restrict__ c1b,
    const float* __restrict__ c2w, const float* __restrict__ c2b,
    const float* __restrict__ in_w, const float* __restrict__ in_b,   // layer 0
    float* __restrict__ x, u16* __restrict__ Qb, u16* __restrict__ Kb,
    u16* __restrict__ Vc, u16* __restrict__ V16)
{
    const int tid = threadIdx.x;
    __shared__ float obsp[2][10][10];
    __shared__ float h1p[16][10][10];
    __shared__ float cs[64][17];
    const int sb = blockIdx.x;                // 0..63
    const int t0 = sb * 64;

    for (int e = tid; e < 200; e += 1024) ((float*)obsp)[e] = 0.f;
    for (int e = tid; e < 1600; e += 1024) ((float*)h1p)[e] = 0.f;
    __syncthreads();
    if (tid < 128) {
        int i = tid >> 6, n = tid & 63, y = n >> 3, xx = n & 7;
        obsp[i][y + 1][xx + 1] = obs[tid];
    }
    __syncthreads();
    {   // conv1
        int o = tid >> 6, n = tid & 63, y = n >> 3, xx = n & 7;
        float a = c1b[o];
        #pragma unroll
        for (int i = 0; i < 2; ++i)
            #pragma unroll
            for (int ky = 0; ky < 3; ++ky)
                #pragma unroll
                for (int kx = 0; kx < 3; ++kx)
                    a = fmaf(obsp[i][y + ky][xx + kx], c1w[((o*2 + i)*3 + ky)*3 + kx], a);
        h1p[o][y + 1][xx + 1] = fmaxf(a, 0.f);
    }
    __syncthreads();
    {   // conv2 -> cs[n][o]
        int o = tid >> 6, n = tid & 63, y = n >> 3, xx = n & 7;
        float a = c2b[o];
        #pragma unroll
        for (int i = 0; i < 16; ++i)
            #pragma unroll
            for (int ky = 0; ky < 3; ++ky)
                #pragma unroll
                for (int kx = 0; kx < 3; ++kx)
                    a = fmaf(h1p[i][y + ky][xx + kx], c2w[((o*16 + i)*3 + ky)*3 + kx], a);
        cs[n][o] = fmaxf(a, 0.f);
    }
    __syncthreads();
    for (int e = tid; e < 64 * DIM; e += 1024) {
        int tl = e / DIM, d = e % DIM;
        int t = t0 + tl, i = t >> 6, j = t & 63;
        float v;
        if (d < 16)       v = cs[i][d];
        else if (d < 32)  v = cs[j][d - 16];
        else if (d == 32) v = (float)((i >> 3) - (j >> 3)) * (1.0f / 3.5f);
        else              v = (float)((i & 7) - (j & 7)) * (1.0f / 3.5f);
        x[t0 * DIM + e] = v;
    }
    // emit layer-0 qkv (slot wave-uniform). Pad col 17: Q=-8, K=1.
    for (int ii = 0; ii < 11; ++ii) {
        int e = tid + ii * 1024;
        if (e >= 64 * 162) break;
        int t = t0 + (e & 63), slot = e >> 6;
        int i = t >> 6, j = t & 63;
        float dx = (float)((i >> 3) - (j >> 3)) * (1.0f / 3.5f);
        float dy = (float)((i & 7) - (j & 7)) * (1.0f / 3.5f);
        if (slot < 128) {
            int isK = slot >> 6, h2 = (slot >> 5) & 1, hs = slot & 31;
            float val = 0.f;
            if (hs < HD) {
                int row = isK*DIM + h2*HD + hs;
                const float* wr = in_w + row*DIM;
                float a = in_b[row];
                #pragma unroll
                for (int d = 0; d < 16; ++d) a = fmaf(cs[i][d], wr[d], a);
                #pragma unroll
                for (int d = 0; d < 16; ++d) a = fmaf(cs[j][d], wr[16 + d], a);
                a = fmaf(dx, wr[32], a);
                a = fmaf(dy, wr[33], a);
                val = isK ? a : a * SC2;
            } else if (hs == HD) {
                val = isK ? 1.0f : -8.0f;     // fixed softmax offset
            }
            u16* dst = isK ? Kb : Qb;
            dst[(((size_t)h2*SEQ + t) << 5) + hs] = f2bf(val);
        } else {
            int s = slot - 128;
            int h2 = s >= HD, dd = s - h2*HD;
            int row = 2*DIM + h2*HD + dd;
            const float* wr = in_w + row*DIM;
            float a = in_b[row];
            #pragma unroll
            for (int d = 0; d < 16; ++d) a = fmaf(cs[i][d], wr[d], a);
            #pragma unroll
            for (int d = 0; d < 16; ++d) a = fmaf(cs[j][d], wr[16 + d], a);
            a = fmaf(dx, wr[32], a);
            a = fmaf(dy, wr[33], a);
            u16 v = f2bf(a);
            if (dd == 16) V16[h2*SEQ + t] = v;
            else {
                int c = t >> 5, g = (t >> 3) & 3, ix = t & 7;
                Vc[((((size_t)h2*128 + c)*4 + g)*16 + dd)*8 + ix] = v;
            }
        }
    }
}

// ---------------------------------------------------------------------------
// Kernel 2: wm_attn3 — MFMA flash attention (fixed-offset softmax, lsum via
// ones-row PV) + out-proj + residual + LN1, in-place on x. 16 waves: wave wv
// -> head wv>>3, key range (wv&7)*512. Layer-0 launch carries NWCONV extra
// blocks (qt >= NQT) that repack FFN weights to bf16 and exit — consumed only
// by wm_ff3, which launches after this kernel drains.
// ---------------------------------------------------------------------------
__global__ __launch_bounds__(1024) void wm_attn3(const u16* __restrict__ Qb,
        const u16* __restrict__ Kb, const u16* __restrict__ Vc,
        const u16* __restrict__ V16, float* __restrict__ x,
        const float* __restrict__ ow, const float* __restrict__ obias,
        const float* __restrict__ g, const float* __restrict__ be,
        const float* __restrict__ w1a, const float* __restrict__ b1a, const float* __restrict__ w2a,
        const float* __restrict__ w1b, const float* __restrict__ b1b, const float* __restrict__ w2b,
        u16* __restrict__ W1A, u16* __restrict__ W2A,
        u16* __restrict__ W1B, u16* __restrict__ W2B)
{
    const int qt = blockIdx.x;
    const int tid = threadIdx.x;
    if (qt >= NQT) {
        // ---- weight repack (layer-0 launch only) ----
        int id = (qt - NQT) * 1024 + tid;
        const int half = W1B_ELEMS + W2B_ELEMS;
        const float* w1 = w1a; const float* b1 = b1a; const float* w2 = w2a;
        u16* W1 = W1A; u16* W2 = W2A;
        if (id >= half) { id -= half; w1 = w1b; b1 = b1b; w2 = w2b; W1 = W1B; W2 = W2B; }
        if (id < W1B_ELEMS) {
            int n = id >> 6, c = id & 63;
            float v = (c < DIM) ? w1[n*DIM + c] : ((c == DIM) ? b1[n] : 0.f);
            W1[id] = f2bf(v);
        } else {
            int e = id - W1B_ELEMS;
            int n = e >> 11;
            float v = (n < DIM) ? w2[(n << 11) + (e & 2047)] : 0.f;
            W2[e] = f2bf(v);
        }
        return;
    }
    const int wv = tid >> 6, l = tid & 63;
    const int h = wv >> 3, rr = wv & 7;
    const int q = l & 15, gg = l >> 4;

    __shared__ float red[16][64][7];   // {lsum, olo0..3, ohi0}
    __shared__ float os[16][DIM];
    __shared__ float ys[16][DIM];
    __shared__ float stats[16][2];

    const u16* Qh = Qb + (((size_t)h*SEQ + qt*16 + q) << 5) + 8*gg;
    const u16* Kh = Kb + ((size_t)h*SEQ << 5);
    const u16* Vh = Vc + (size_t)h*128*512;
    const u16* V6 = V16 + (size_t)h*SEQ;

    const bf16x8 qf = *(const bf16x8*)Qh;
    const f32x4 zero4 = {0.f, 0.f, 0.f, 0.f};
    bf16x8 onesv;
    { union { uint32_t u[4]; bf16x8 v; } o1;
      o1.u[0] = o1.u[1] = o1.u[2] = o1.u[3] = 0x3F803F80u; onesv = o1.v; }

    f32x4 olo = zero4, ohi = zero4;
    const int srcA = q + 32*(gg & 1);
    const int srcB = srcA + 16;
    const bool hi = (gg >= 2);

    for (int it = 0; it < 8; ++it) {
        const int cA = rr*16 + it*2;
        const int k0 = cA * 32;
        bf16x8 kf0 = *(const bf16x8*)(Kh + ((size_t)(k0 + q) << 5) + 8*gg);
        bf16x8 kf1 = *(const bf16x8*)(Kh + ((size_t)(k0 + 16 + q) << 5) + 8*gg);
        bf16x8 kf2 = *(const bf16x8*)(Kh + ((size_t)(k0 + 32 + q) << 5) + 8*gg);
        bf16x8 kf3 = *(const bf16x8*)(Kh + ((size_t)(k0 + 48 + q) << 5) + 8*gg);
        f32x4 s0 = MFMA16(kf0, qf, zero4);
        f32x4 s1 = MFMA16(kf1, qf, zero4);
        f32x4 s2 = MFMA16(kf2, qf, zero4);
        f32x4 s3 = MFMA16(kf3, qf, zero4);
        float pa0 = EXP2F(s0[0]), pa1 = EXP2F(s0[1]), pa2 = EXP2F(s0[2]), pa3 = EXP2F(s0[3]);
        float pa4 = EXP2F(s1[0]), pa5 = EXP2F(s1[1]), pa6 = EXP2F(s1[2]), pa7 = EXP2F(s1[3]);
        float pb0 = EXP2F(s2[0]), pb1 = EXP2F(s2[1]), pb2 = EXP2F(s2[2]), pb3 = EXP2F(s2[3]);
        float pb4 = EXP2F(s3[0]), pb5 = EXP2F(s3[1]), pb6 = EXP2F(s3[2]), pb7 = EXP2F(s3[3]);
        {   // chunk A
            uint32_t a0t0 = pack2(pa0, pa1), a1t0 = pack2(pa2, pa3);
            uint32_t a0t1 = pack2(pa4, pa5), a1t1 = pack2(pa6, pa7);
            uint32_t w0a = (uint32_t)__shfl((int)a0t0, srcA), w0b = (uint32_t)__shfl((int)a0t1, srcA);
            uint32_t w1a_ = (uint32_t)__shfl((int)a1t0, srcA), w1b_ = (uint32_t)__shfl((int)a1t1, srcA);
            uint32_t w2a_ = (uint32_t)__shfl((int)a0t0, srcB), w2b_ = (uint32_t)__shfl((int)a0t1, srcB);
            uint32_t w3a = (uint32_t)__shfl((int)a1t0, srcB), w3b = (uint32_t)__shfl((int)a1t1, srcB);
            union { uint32_t u[4]; bf16x8 v; } pu;
            pu.u[0] = hi ? w0b : w0a;
            pu.u[1] = hi ? w1b_ : w1a_;
            pu.u[2] = hi ? w2b_ : w2a_;
            pu.u[3] = hi ? w3b : w3a;
            bf16x8 vf = *(const bf16x8*)(Vh + (size_t)(cA*4 + gg)*128 + q*8);
            bf16x8 v6 = {};
            if (q == 0) v6 = *(const bf16x8*)(V6 + k0 + 8*gg);
            else if (q == 1) v6 = onesv;          // row 1 = ones -> ohi[1] = lsum
            olo = MFMA16(vf, pu.v, olo);
            ohi = MFMA16(v6, pu.v, ohi);
        }
        {   // chunk B
            uint32_t a0t0 = pack2(pb0, pb1), a1t0 = pack2(pb2, pb3);
            uint32_t a0t1 = pack2(pb4, pb5), a1t1 = pack2(pb6, pb7);
            uint32_t w0a = (uint32_t)__shfl((int)a0t0, srcA), w0b = (uint32_t)__shfl((int)a0t1, srcA);
            uint32_t w1a_ = (uint32_t)__shfl((int)a1t0, srcA), w1b_ = (uint32_t)__shfl((int)a1t1, srcA);
            uint32_t w2a_ = (uint32_t)__shfl((int)a0t0, srcB), w2b_ = (uint32_t)__shfl((int)a0t1, srcB);
            uint32_t w3a = (uint32_t)__shfl((int)a1t0, srcB), w3b = (uint32_t)__shfl((int)a1t1, srcB);
            union { uint32_t u[4]; bf16x8 v; } pu;
            pu.u[0] = hi ? w0b : w0a;
            pu.u[1] = hi ? w1b_ : w1a_;
            pu.u[2] = hi ? w2b_ : w2a_;
            pu.u[3] = hi ? w3b : w3a;
            bf16x8 vf = *(const bf16x8*)(Vh + (size_t)((cA + 1)*4 + gg)*128 + q*8);
            bf16x8 v6 = {};
            if (q == 0) v6 = *(const bf16x8*)(V6 + k0 + 32 + 8*gg);
            else if (q == 1) v6 = onesv;
            olo = MFMA16(vf, pu.v, olo);
            ohi = MFMA16(v6, pu.v, ohi);
        }
    }

    {
        float* r = red[wv][l];
        r[0] = ohi[1];                  // lsum partial (nonzero on gg==0 lanes)
        r[1] = olo[0]; r[2] = olo[1]; r[3] = olo[2]; r[4] = olo[3];
        r[5] = ohi[0];
    }
    __syncthreads();
    if (rr == 0) {
        float lt = 0.f, o0 = 0.f, o1 = 0.f, o2 = 0.f, o3 = 0.f, o6 = 0.f;
        #pragma unroll
        for (int p = 0; p < 8; ++p) {
            float* r = red[wv + p][l];
            lt += r[0]; o0 += r[1]; o1 += r[2]; o2 += r[3]; o3 += r[4]; o6 += r[5];
        }
        lt += __shfl_xor(lt, 16);
        lt += __shfl_xor(lt, 32);
        float inv = 1.f / lt;
        os[q][h*HD + 4*gg + 0] = o0*inv;
        os[q][h*HD + 4*gg + 1] = o1*inv;
        os[q][h*HD + 4*gg + 2] = o2*inv;
        os[q][h*HD + 4*gg + 3] = o3*inv;
        if (gg == 0) os[q][h*HD + 16] = o6*inv;
    }
    __syncthreads();
    // out-proj + residual
    for (int e = tid; e < 16 * DIM; e += 1024) {
        int tt = e / DIM, d = e % DIM;
        const float* wr = ow + d*DIM;
        float acc = obias[d];
        #pragma unroll
        for (int k = 0; k < DIM; ++k) acc = fmaf(os[tt][k], wr[k], acc);
        ys[tt][d] = x[(size_t)(qt*16 + tt)*DIM + d] + acc;
    }
    __syncthreads();
    if (tid < 16) {
        float s1 = 0.f, s2 = 0.f;
        #pragma unroll
        for (int d = 0; d < DIM; ++d) { float v = ys[tid][d]; s1 += v; s2 += v*v; }
        float mean = s1 * (1.0f / DIM);
        float var  = s2 * (1.0f / DIM) - mean*mean;
        stats[tid][0] = mean;
        stats[tid][1] = rsqrtf(var + 1e-5f);
    }
    __syncthreads();
    for (int e = tid; e < 16 * DIM; e += 1024) {
        int tt = e / DIM, d = e % DIM;
        x[(size_t)(qt*16 + tt)*DIM + d] = (ys[tt][d] - stats[tt][0]) * stats[tt][1] * g[d] + be[d];
    }
}

// ---------------------------------------------------------------------------
// Kernel 3: wm_ff3 — MFMA fused FFN + residual + LN2 (+ optional next-layer
// QKV emit). No fences, no atomics.
// ---------------------------------------------------------------------------
__global__ __launch_bounds__(1024) void wm_ff3(float* __restrict__ x,
        const u16* __restrict__ W1b, const u16* __restrict__ W2b,
        const float* __restrict__ b2, const float* __restrict__ g,
        const float* __restrict__ be,
        const float* __restrict__ in_w, const float* __restrict__ in_b,
        u16* __restrict__ Qb, u16* __restrict__ Kb,
        u16* __restrict__ Vc, u16* __restrict__ V16, int do_qkv)
{
    __shared__ u16 Hs[16][16][128];      // 64 KB, wave-private, XOR-swizzled
    __shared__ float red[16][16][52];    // 53 KB
    __shared__ float ys[16][DIM];
    __shared__ float stats[16][2];
    const int tid = threadIdx.x, wv = tid >> 6, l = tid & 63;
    const int q = l & 15, g4 = l >> 4;
    const int t0 = blockIdx.x * 16;

    const float* xr = x + (size_t)(t0 + q) * DIM;
    union { uint32_t u[4]; bf16x8 v; } a0, a1;
    #pragma unroll
    for (int j = 0; j < 4; ++j)
        a0.u[j] = pack2(xr[g4*8 + 2*j], xr[g4*8 + 2*j + 1]);
    a1.u[0] = 0; a1.u[1] = 0; a1.u[2] = 0; a1.u[3] = 0;
    if (g4 == 0) {
        a1.u[0] = pack2(xr[32], xr[33]);
        a1.u[1] = pack2(1.0f, 0.f);      // col 34 = bias slot
    }
    const f32x4 zero4 = {0.f, 0.f, 0.f, 0.f};

    const int hbase = wv * 128;
    #pragma unroll
    for (int nt = 0; nt < 8; ++nt) {
        const u16* brow = W1b + (size_t)(hbase + nt*16 + q) * 64 + g4*8;
        bf16x8 b0 = *(const bf16x8*)brow;
        bf16x8 b1f = *(const bf16x8*)(brow + 32);
        f32x4 c = MFMA16(a0.v, b0, zero4);
        c = MFMA16(a1.v, b1f, c);
        #pragma unroll
        for (int r = 0; r < 4; ++r) {
            int mm = 4*g4 + r;
            int byte = ((nt*16 + q) * 2) ^ ((mm & 7) << 4);
            *(u16*)((char*)&Hs[wv][mm][0] + byte) = f2bf(fmaxf(c[r], 0.f));
        }
    }
    asm volatile("s_waitcnt lgkmcnt(0)" ::: "memory");
    __builtin_amdgcn_sched_barrier(0);
    f32x4 acc0 = zero4, acc1 = zero4, acc2 = zero4;
    #pragma unroll
    for (int ks = 0; ks < 4; ++ks) {
        int byte = (ks*64 + g4*16) ^ ((q & 7) << 4);
        bf16x8 af = *(const bf16x8*)((char*)&Hs[wv][q][0] + byte);
        const u16* bp = W2b + (size_t)q * FFDIM + hbase + ks*32 + g4*8;
        acc0 = MFMA16(af, *(const bf16x8*)bp, acc0);
        acc1 = MFMA16(af, *(const bf16x8*)(bp + 16*FFDIM), acc1);
        acc2 = MFMA16(af, *(const bf16x8*)(bp + 32*FFDIM), acc2);
    }
    #pragma unroll
    for (int r = 0; r < 4; ++r) {
        red[wv][4*g4 + r][q]      = acc0[r];
        red[wv][4*g4 + r][16 + q] = acc1[r];
        red[wv][4*g4 + r][32 + q] = acc2[r];
    }
    __syncthreads();
    for (int e = tid; e < 16*DIM; e += 1024) {
        int tt = e / DIM, d = e % DIM;
        float v = x[(size_t)(t0 + tt)*DIM + d] + b2[d];
        #pragma unroll
        for (int w = 0; w < 16; ++w) v += red[w][tt][d];
        ys[tt][d] = v;
    }
    __syncthreads();
    if (tid < 16) {
        float s1 = 0.f, s2 = 0.f;
        #pragma unroll
        for (int d = 0; d < DIM; ++d) { float v = ys[tid][d]; s1 += v; s2 += v * v; }
        float mean = s1 * (1.0f / DIM);
        float var  = s2 * (1.0f / DIM) - mean * mean;
        stats[tid][0] = mean;
        stats[tid][1] = rsqrtf(var + 1e-5f);
    }
    __syncthreads();
    for (int e = tid; e < 16*DIM; e += 1024) {
        int tt = e / DIM, d = e % DIM;
        float v = (ys[tt][d] - stats[tt][0]) * stats[tt][1] * g[d] + be[d];
        x[(size_t)(t0 + tt)*DIM + d] = v;
        ys[tt][d] = v;                   // final x tile kept in LDS for qkv
    }
    if (do_qkv) {
        __syncthreads();
        #pragma unroll
        for (int ii = 0; ii < 2; ++ii) {
            int e = tid + ii*1024;
            if (e < 16*102) {
                int r = e >> 4, tt = e & 15;
                const float* wr = in_w + r*DIM;
                float a = in_b[r];
                #pragma unroll
                for (int d = 0; d < DIM; ++d) a = fmaf(ys[tt][d], wr[d], a);
                int tg = t0 + tt;
                if (r < 68) {
                    int rq = (r < 34) ? r : r - 34;
                    int h2 = rq >= HD, hs = rq - h2*HD;
                    u16 v = f2bf((r < 34) ? a*SC2 : a);
                    u16* dst = (r < 34) ? Qb : Kb;
                    dst[(((size_t)h2*SEQ + tg) << 5) + hs] = v;
                } else {
                    int rv = r - 68;
                    int h2 = rv >= HD, dd = rv - h2*HD;
                    u16 v = f2bf(a);
                    if (dd == 16) V16[h2*SEQ + tg] = v;
                    else {
                        int c = tg >> 5, gg = (tg >> 3) & 3, ix = tg & 7;
                        Vc[((((size_t)h2*128 + c)*4 + gg)*16 + dd)*8 + ix] = v;
                    }
                }
            }
        }
    }
}

// ---------------------------------------------------------------------------
// Kernel 4: final head (+ agent argmax + action embedding)
// ---------------------------------------------------------------------------
__global__ __launch_bounds__(64) void wm_final(const float* __restrict__ x,
        const float* __restrict__ obs, const int* __restrict__ action,
        const float* __restrict__ aw, const float* __restrict__ ab,
        const float* __restrict__ hw, const float* __restrict__ hb,
        float* __restrict__ out)
{
    __shared__ float hv[DIM];
    __shared__ float saemb[8];
    __shared__ int sai;
    const int tid = threadIdx.x;
    {
        float v = obs[tid];
        float mx = v;
        for (int off = 32; off; off >>= 1) mx = fmaxf(mx, __shfl_xor(mx, off));
        unsigned long long mask = __ballot(v == mx);
        if (tid == 0) sai = (int)(__ffsll(mask) - 1);
    }
    if (tid < 8) {
        int act = *action;
        saemb[tid] = fmaxf(aw[tid*4 + act] + ab[tid], 0.f);
    }
    __syncthreads();
    const int ai = sai;
    if (tid < DIM) {
        float s = 0.f;
        for (int r = 0; r < 64; ++r) s += x[(size_t)(ai*64 + r)*DIM + tid];
        hv[tid] = s * (1.0f / 64.0f);
    }
    __syncthreads();
    if (tid < 16) {
        float a = hb[tid];
        #pragma unroll
        for (int d = 0; d < DIM; ++d) a = fmaf(hv[d], hw[tid*42 + d], a);
        #pragma unroll
        for (int j = 0; j < 8; ++j) a = fmaf(saemb[j], hw[tid*42 + DIM + j], a);
        out[tid] = a;
    }
}

// ---------------------------------------------------------------------------
extern "C" void kernel_launch(void* const* d_in, const int* in_sizes, int n_in,
                              void* d_out, int out_size, void* d_ws, size_t ws_size,
                              hipStream_t stream)
{
    const float* obs    = (const float*)d_in[0];
    const int*   action = (const int*)  d_in[1];

    float* ws   = (float*)d_ws;
    float* x    = ws + 1056;                // 4096*34
    float* o    = x + SEQ * DIM;            // (unused spacing)
    u16*   Qb   = (u16*)(o + SEQ * DIM);    // 2*4096*32 bf16
    u16*   Kb   = Qb + 2 * SEQ * 32;
    u16*   Vc   = Kb + 2 * SEQ * 32;        // 2*128*4*16*8 bf16
    u16*   V16  = Vc + 2 * 128 * 512;       // 2*4096 bf16
    u16*   W1b0 = V16 + 2 * SEQ;
    u16*   W2b0 = W1b0 + W1B_ELEMS;
    u16*   W1b1 = W2b0 + W2B_ELEMS;
    u16*   W2b1 = W1b1 + W1B_ELEMS;

    wm_pre<<<64, 1024, 0, stream>>>(
        obs, (const float*)d_in[2], (const float*)d_in[3],
        (const float*)d_in[4], (const float*)d_in[5],
        (const float*)d_in[6], (const float*)d_in[7],
        x, Qb, Kb, Vc, V16);

    // layer 0 attn (+ hidden weight repack in extra blocks)
    wm_attn3<<<NQT + NWCONV, 1024, 0, stream>>>(Qb, Kb, Vc, V16, x,
        (const float*)d_in[8], (const float*)d_in[9],
        (const float*)d_in[14], (const float*)d_in[15],
        (const float*)d_in[10], (const float*)d_in[11], (const float*)d_in[12],
        (const float*)d_in[22], (const float*)d_in[23], (const float*)d_in[24],
        W1b0, W2b0, W1b1, W2b1);

    wm_ff3<<<NQT, 1024, 0, stream>>>(x, W1b0, W2b0,
        (const float*)d_in[13], (const float*)d_in[16], (const float*)d_in[17],
        (const float*)d_in[18], (const float*)d_in[19],
        Qb, Kb, Vc, V16, 1);

    // layer 1 attn (no repack blocks)
    wm_attn3<<<NQT, 1024, 0, stream>>>(Qb, Kb, Vc, V16, x,
        (const float*)d_in[20], (const float*)d_in[21],
        (const float*)d_in[26], (const float*)d_in[27],
        (const float*)d_in[10], (const float*)d_in[11], (const float*)d_in[12],
        (const float*)d_in[22], (const float*)d_in[23], (const float*)d_in[24],
        W1b0, W2b0, W1b1, W2b1);

    wm_ff3<<<NQT, 1024, 0, stream>>>(x, W1b1, W2b1,
        (const float*)d_in[25], (const float*)d_in[28], (const float*)d_in[29],
        (const float*)d_in[18], (const float*)d_in[19],
        Qb, Kb, Vc, V16, 0);

    wm_final<<<1, 64, 0, stream>>>(x, obs, action,
        (const float*)d_in[30], (const float*)d_in[31],
        (const float*)d_in[32], (const float*)d_in[33], (float*)d_out);
}